// Round 8
// baseline (448.708 us; speedup 1.0000x reference)
//
#include <hip/hip_runtime.h>
#include <hip/hip_bf16.h>
#include <stdint.h>

#define N_USERC  50000
#define N_MERCHC 50000
#define NEC      1000000   // edges per direction
#define NTC      500000    // target edges

#define DCAP  64           // direct per-dst bin slots (deg ~ Poisson(20); P(>64) ~ 2e-15)
#define NB    196          // target buckets (256 users each: bucket = r >> 8)
#define TCAP  4096         // target pairs per bucket (mean 2560, +30 sigma)
#define ECHUNK 2048        // edges per pass block (8/thread)
#define BPT   489          // direct-place blocks per edge type = ceil(NEC/ECHUNK)
#define BPTT  245          // target bucket-pass blocks = ceil(NTC/ECHUNK)

// k_prep fused-grid offsets — edge passes FIRST (long pole starts at t=0)
#define PREP_BKT   (2 * BPT + BPTT)       // [0, 1223) edge passes (um, mu direct; tgt bucket)
#define PREP_CASTX (PREP_BKT + 3125)      // x casts  (800000/256 blocks)
#define PREP_CASTW (PREP_CASTX + 16)      // layer-1 weight casts
#define PREP_TOT   (PREP_CASTW + 257)     // classifier weight fusion

typedef unsigned short ushortT;
typedef __attribute__((ext_vector_type(8))) short short8;     // 8 bf16 (MFMA frag)
typedef __attribute__((ext_vector_type(8))) unsigned short ushort8;
typedef __attribute__((ext_vector_type(4))) float f32x4;
typedef __attribute__((ext_vector_type(2))) float f32x2;

__device__ __forceinline__ unsigned short f2bf(float f)
{
    const unsigned u = __float_as_uint(f);
    const unsigned r = u + 0x7fffu + ((u >> 16) & 1u);   // RNE
    return (unsigned short)(r >> 16);
}
__device__ __forceinline__ float bfhi(unsigned u) { return __uint_as_float(u & 0xffff0000u); }
__device__ __forceinline__ float bflo(unsigned u) { return __uint_as_float(u << 16); }

// packed accumulate: 4x v_pk_add_f32 + 8 unpacks per 16B
__device__ __forceinline__ void acc8p(f32x2* a, const uint4 v)
{
    a[0] += (f32x2){bflo(v.x), bfhi(v.x)};
    a[1] += (f32x2){bflo(v.y), bfhi(v.y)};
    a[2] += (f32x2){bflo(v.z), bfhi(v.z)};
    a[3] += (f32x2){bflo(v.w), bfhi(v.w)};
}

// relu(p+q).w over 8 bf16 pairs
__device__ __forceinline__ float edot8(const uint4 pv, const uint4 qv,
                                       const float4 w0, const float4 w1)
{
    return fmaxf(bflo(pv.x) + bflo(qv.x), 0.f) * w0.x
         + fmaxf(bfhi(pv.x) + bfhi(qv.x), 0.f) * w0.y
         + fmaxf(bflo(pv.y) + bflo(qv.y), 0.f) * w0.z
         + fmaxf(bfhi(pv.y) + bfhi(qv.y), 0.f) * w0.w
         + fmaxf(bflo(pv.z) + bflo(qv.z), 0.f) * w1.x
         + fmaxf(bfhi(pv.z) + bfhi(qv.z), 0.f) * w1.y
         + fmaxf(bflo(pv.w) + bflo(qv.w), 0.f) * w1.z
         + fmaxf(bfhi(pv.w) + bfhi(qv.w), 0.f) * w1.w;
}

// ---------------------------------------------------------------------------
// Fused prep kernel: blockIdx ranges dispatch independent jobs.
//  [0, 978)       um/mu DIRECT placement: srcs[dst*64 + atomicAdd(cnt[dst])]
//                 = src. No LDS hist, no bucket round-trip, no place kernel.
//                 (deg Poisson(20): P(>64) ~ 2e-15 -> 64-slot bins safe.)
//  [978, 1223)    TARGET bucket append (u64 rl<<40|eid<<20|c), as R7 —
//                 consumed bucket-direct + XCD-pinned by k_edge_bkt.
//  [1223, 4348)   cast x tables -> interleaved A1 ([mean1 | x], bf16)
//  [4348, 4364)   cast layer-1 weights -> B1 ([Wl | Wr] along K, bf16)
//  [4364, 4621)   fused classifier weights WPQ/bPQ (z never materialized)
// ---------------------------------------------------------------------------
__global__ __launch_bounds__(256) void k_prep(
    const float* __restrict__ xu, const float* __restrict__ xm,
    ushortT* __restrict__ A1u, ushortT* __restrict__ A1m,
    const float* __restrict__ W1um_l, const float* __restrict__ W1um_r,
    const float* __restrict__ W1mu_l, const float* __restrict__ W1mu_r,
    ushortT* __restrict__ B1m, ushortT* __restrict__ B1u,
    const float* __restrict__ Wc1,
    const float* __restrict__ W2mu_l, const float* __restrict__ W2mu_r,
    const float* __restrict__ W2um_l, const float* __restrict__ W2um_r,
    const float* __restrict__ bc1,
    const float* __restrict__ b2mu_l, const float* __restrict__ b2um_l,
    ushortT* __restrict__ WPQ, float* __restrict__ bPQ,
    const int* __restrict__ rowA, const int* __restrict__ colA,
    const int* __restrict__ rowB, const int* __restrict__ colB,
    const int* __restrict__ tgr, const int* __restrict__ tgc,
    uint32_t* __restrict__ tcnt, uint32_t* __restrict__ cntA, uint32_t* __restrict__ cntB,
    int* __restrict__ srcsA, int* __restrict__ srcsB, uint64_t* __restrict__ bktT)
{
    __shared__ uint32_t hist[NB], base[NB], cur[NB];
    const int bid = blockIdx.x;
    const int tx = threadIdx.x;

    if (bid < 2 * BPT) {
        // ---- um/mu DIRECT placement (no LDS, no sync)
        const int type = (bid >= BPT) ? 1 : 0;
        const int cb = bid - type * BPT;
        const int* col = type ? colB : colA;    // dst (bin key)
        const int* row = type ? rowB : rowA;    // src (payload)
        uint32_t* cnt = type ? cntB : cntA;
        int* sdir     = type ? srcsB : srcsA;

        const int e0 = cb * ECHUNK;
        const int e1 = (e0 + ECHUNK < NEC) ? e0 + ECHUNK : NEC;

        int cols[8], rows[8];
#pragma unroll
        for (int q = 0; q < 8; ++q) {
            const int i = e0 + tx + q * 256;
            cols[q] = (i < e1) ? col[i] : -1;
            rows[q] = (i < e1) ? row[i] : 0;
        }
        uint32_t p[8];
#pragma unroll
        for (int q = 0; q < 8; ++q)
            if (cols[q] >= 0) p[q] = atomicAdd(&cnt[cols[q]], 1u);
#pragma unroll
        for (int q = 0; q < 8; ++q)
            if (cols[q] >= 0 && p[q] < (uint32_t)DCAP)
                sdir[(size_t)cols[q] * DCAP + p[q]] = rows[q];
    } else if (bid < PREP_BKT) {
        // ---- TARGET bucket append (LDS hist for contiguous runs)
        const int cb = bid - 2 * BPT;
        const int e0 = cb * ECHUNK;
        const int e1 = (e0 + ECHUNK < NTC) ? e0 + ECHUNK : NTC;

        for (int i = tx; i < NB; i += 256) { hist[i] = 0; cur[i] = 0; }
        __syncthreads();

        int rs[8];
#pragma unroll
        for (int q = 0; q < 8; ++q) {
            const int i = e0 + tx + q * 256;
            int r = -1;
            if (i < e1) { r = tgr[i]; atomicAdd(&hist[r >> 8], 1u); }
            rs[q] = r;
        }
        __syncthreads();
        for (int i = tx; i < NB; i += 256)
            base[i] = atomicAdd(&tcnt[i], hist[i]);
        __syncthreads();
#pragma unroll
        for (int q = 0; q < 8; ++q) {
            const int i = e0 + tx + q * 256;
            if (i < e1) {
                const int r = rs[q];
                const int b = r >> 8;
                const uint32_t p = base[b] + atomicAdd(&cur[b], 1u);
                if (p < (uint32_t)TCAP)
                    bktT[(size_t)b * TCAP + p] = ((uint64_t)(r & 255) << 40)
                                               | ((uint64_t)(uint32_t)i << 20)
                                               | (uint64_t)(uint32_t)tgc[i];
            }
        }
    } else if (bid < PREP_CASTX) {
        // ---- cast_x: A1[row] = [ (mean later) | bf16(x[row]) ]
        const int idx = (bid - PREP_BKT) * 256 + tx;
        if (idx >= 800000) return;
        const int which = idx / 400000;
        const int rem = idx - which * 400000;
        const int row = rem >> 3;
        const int c8 = rem & 7;
        const float* x = which ? xm : xu;
        ushortT* A = which ? A1m : A1u;
        const float4 v0 = *(const float4*)(x + (size_t)row * 64 + c8 * 8);
        const float4 v1 = *(const float4*)(x + (size_t)row * 64 + c8 * 8 + 4);
        ushort8 o;
        o[0] = f2bf(v0.x); o[1] = f2bf(v0.y); o[2] = f2bf(v0.z); o[3] = f2bf(v0.w);
        o[4] = f2bf(v1.x); o[5] = f2bf(v1.y); o[6] = f2bf(v1.z); o[7] = f2bf(v1.w);
        *(ushort8*)(A + (size_t)row * 128 + 64 + c8 * 8) = o;
    } else if (bid < PREP_CASTW) {
        // ---- cast_w1: B1[n][k] = k<64 ? Wl[n][k] : Wr[n][k-64]
        const int idx = (bid - PREP_CASTX) * 256 + tx;
        if (idx >= 4096) return;
        const int which = idx >> 11;
        const int rem = idx & 2047;
        const int n = rem >> 4;
        const int k0 = (rem & 15) * 8;
        const float* Wl = which ? W1mu_l : W1um_l;
        const float* Wr = which ? W1mu_r : W1um_r;
        const float* src = (k0 < 64) ? Wl + (size_t)n * 64 + k0
                                     : Wr + (size_t)n * 64 + (k0 - 64);
        const float4 v0 = *(const float4*)src;
        const float4 v1 = *(const float4*)(src + 4);
        ushort8 o;
        o[0] = f2bf(v0.x); o[1] = f2bf(v0.y); o[2] = f2bf(v0.z); o[3] = f2bf(v0.w);
        o[4] = f2bf(v1.x); o[5] = f2bf(v1.y); o[6] = f2bf(v1.z); o[7] = f2bf(v1.w);
        ushortT* O = which ? B1u : B1m;
        *(ushort8*)(O + (size_t)n * 128 + k0) = o;
    } else {
        // ---- wcombine: WP[j][k] = Wc1a[j,:] @ W2_mu_{l|r}[:,k] etc., bf16
        const int idx = (bid - PREP_CASTW) * 256 + tx;
        if (idx < 65536) {
            const int q = idx >> 15;
            const int j = (idx >> 8) & 127;
            const int k = idx & 255;
            const int kk = k & 127;
            const float* W2 = q ? (k < 128 ? W2um_l : W2um_r)
                                : (k < 128 ? W2mu_l : W2mu_r);
            const float* wrow = Wc1 + (size_t)j * 256 + q * 128;
            float s = 0.f;
            for (int i = 0; i < 128; ++i)
                s = fmaf(wrow[i], W2[(size_t)i * 128 + kk], s);
            WPQ[idx] = f2bf(s);
        } else if (idx < 65536 + 256) {
            const int r = idx - 65536;
            const int q = r >> 7, j = r & 127;
            const float* wrow = Wc1 + (size_t)j * 256 + q * 128;
            const float* b2 = q ? b2um_l : b2mu_l;
            float s = (q == 0) ? bc1[j] : 0.f;
            for (int i = 0; i < 128; ++i) s = fmaf(wrow[i], b2[i], s);
            bPQ[r] = s;
        }
    }
}

// ---------------------------------------------------------------------------
// Mean aggregation over interleaved bf16 tables, both directions per launch.
// Direct-bin adjacency: dst's list at srcs[wid*64], degree in cnt[wid]
// (deg <= 64 guaranteed by bin cap). R3 gather loop (fabric-bound opt).
// ---------------------------------------------------------------------------
template <int D>
__global__ __launch_bounds__(256) void k_agg(
    const ushortT* __restrict__ gA, const uint32_t* __restrict__ cntA,
    const int* __restrict__ srcsA, ushortT* __restrict__ oA,
    const ushortT* __restrict__ gB, const uint32_t* __restrict__ cntB,
    const int* __restrict__ srcsB, ushortT* __restrict__ oB, int ndst)
{
    constexpr int LPE = D / 8;        // lanes per edge row (16 / 8)
    constexpr int EPW = 64 / LPE;     // edges per round (4 / 8)
    constexpr int UNR = (D == 128) ? 8 : 4;   // rounds per chunk
    constexpr int STR = 2 * D;        // interleaved row stride (elems)
    constexpr unsigned RB = 4 * D;    // row stride in bytes
    const int half = gridDim.x >> 1;
    const int type = (blockIdx.x >= half) ? 1 : 0;
    const int cb = blockIdx.x - type * half;
    const ushortT* g = type ? gB : gA;
    const uint32_t* cnt = type ? cntB : cntA;
    const int* srcs  = type ? srcsB : srcsA;
    ushortT* om      = type ? oB : oA;

    const int wid = cb * 4 + (threadIdx.x >> 6);
    if (wid >= ndst) return;
    const int lane = threadIdx.x & 63;
    const int sub  = lane / LPE;
    const int c4   = lane % LPE;

    const int degt = (int)cnt[wid];
    const int deg = (degt < DCAP) ? degt : DCAP;
    const int b = wid * DCAP;
    // per-lane column base: row s contributes bytes [s*RB + 2*D + c4*16, +16)
    const char* gDc = (const char*)(g + D) + c4 * 16;

    f32x2 a0[4], a1[4];
#pragma unroll
    for (int j = 0; j < 4; ++j) { a0[j] = (f32x2){0.f, 0.f}; a1[j] = (f32x2){0.f, 0.f}; }

    // whole bin in registers via one coalesced 256B load + shfl
    const int src_l = srcs[b + lane];
    for (int t0 = 0; t0 < deg; t0 += UNR * EPW) {
        uint4 v[UNR];
#pragma unroll
        for (int r = 0; r < UNR; ++r) {
            const int j = t0 + r * EPW + sub;      // j <= 63 by construction
            const int s = __shfl(src_l, j);
            v[r] = (uint4){0u, 0u, 0u, 0u};
            if (j < deg)
                v[r] = *(const uint4*)(gDc + (unsigned)s * RB);
        }
        __builtin_amdgcn_sched_barrier(0);         // pin: all gathers issued first
#pragma unroll
        for (int r = 0; r < UNR; ++r)
            acc8p((r & 1) ? a1 : a0, v[r]);
    }

    float r[8];
#pragma unroll
    for (int j = 0; j < 4; ++j) {
        r[2 * j]     = a0[j].x + a1[j].x;
        r[2 * j + 1] = a0[j].y + a1[j].y;
    }
#pragma unroll
    for (int m = LPE; m < 64; m <<= 1) {
#pragma unroll
        for (int j = 0; j < 8; ++j) r[j] += __shfl_xor(r[j], m);
    }
    if (sub == 0) {
        const float inv = 1.0f / (float)(degt > 1 ? degt : 1);
        ushort8 o;
#pragma unroll
        for (int j = 0; j < 8; ++j) o[j] = f2bf(r[j] * inv);
        *(ushort8*)(om + (size_t)wid * STR + c4 * 8) = o;
    }
}

// ---------------------------------------------------------------------------
// MFMA bf16 GEMM: Out[m][0:128] = act(A[m][0:K] @ W^T + bias), bf16 out.
// ---------------------------------------------------------------------------
template <int K, bool RELU>
__device__ __forceinline__ void mfma_gemm_body(
    int cb, float (*lds)[16][132],
    const ushortT* __restrict__ A, const ushortT* __restrict__ Bw,
    const float* __restrict__ bias,
    ushortT* __restrict__ Obf, int OS, int OO, int M)
{
    const int tx = threadIdx.x;
    const int wid = tx >> 6;
    const int lane = tx & 63;
    const int ln = lane & 15;
    const int quad = lane >> 4;
    const int m0 = cb * 256 + wid * 64;

    const ushortT* ap[4];
#pragma unroll
    for (int i = 0; i < 4; ++i) {
        int arow = m0 + i * 16 + ln; if (arow >= M) arow = M - 1;
        ap[i] = A + (size_t)arow * K + quad * 8;
    }

    f32x4 acc[4][8];
#pragma unroll
    for (int i = 0; i < 4; ++i)
#pragma unroll
        for (int nt = 0; nt < 8; ++nt) acc[i][nt] = (f32x4){0.f, 0.f, 0.f, 0.f};

#pragma unroll
    for (int kc = 0; kc < K / 32; ++kc) {
        short8 a[4];
#pragma unroll
        for (int i = 0; i < 4; ++i) a[i] = *(const short8*)(ap[i] + kc * 32);
#pragma unroll
        for (int nt = 0; nt < 8; ++nt) {
            const short8 b = *(const short8*)(Bw + (size_t)(nt * 16 + ln) * K + kc * 32 + quad * 8);
#pragma unroll
            for (int i = 0; i < 4; ++i)
                acc[i][nt] = __builtin_amdgcn_mfma_f32_16x16x32_bf16(a[i], b, acc[i][nt], 0, 0, 0);
        }
    }

    float (*t)[132] = lds[wid];
#pragma unroll
    for (int i = 0; i < 4; ++i) {
#pragma unroll
        for (int nt = 0; nt < 8; ++nt) {
            const float bv = bias[nt * 16 + ln];
#pragma unroll
            for (int r = 0; r < 4; ++r) {
                float v = acc[i][nt][r] + bv;
                if (RELU) v = fmaxf(v, 0.f);
                t[quad * 4 + r][nt * 16 + ln] = v;
            }
        }
#pragma unroll
        for (int p = 0; p < 4; ++p) {
            const int row = p * 4 + quad;
            const int gr = m0 + i * 16 + row;
            if (gr < M) {
                const float4 v0 = *(const float4*)&t[row][ln * 8];
                const float4 v1 = *(const float4*)&t[row][ln * 8 + 4];
                ushort8 o;
                o[0] = f2bf(v0.x); o[1] = f2bf(v0.y); o[2] = f2bf(v0.z); o[3] = f2bf(v0.w);
                o[4] = f2bf(v1.x); o[5] = f2bf(v1.y); o[6] = f2bf(v1.z); o[7] = f2bf(v1.w);
                *(ushort8*)(Obf + (size_t)gr * OS + OO + ln * 8) = o;
            }
        }
    }
}

template <int K, bool RELU>
__global__ __launch_bounds__(256) void k_mfma_gemm2(
    const ushortT* __restrict__ Aa, const ushortT* __restrict__ Bwa,
    const float* __restrict__ biasa, ushortT* __restrict__ Oa, int OSa, int OOa, int Ma,
    const ushortT* __restrict__ Ab, const ushortT* __restrict__ Bwb,
    const float* __restrict__ biasb, ushortT* __restrict__ Ob, int OSb, int OOb, int Mb,
    int gridA)
{
    __shared__ float lds[4][16][132];
    if ((int)blockIdx.x < gridA)
        mfma_gemm_body<K, RELU>(blockIdx.x, lds, Aa, Bwa, biasa, Oa, OSa, OOa, Ma);
    else
        mfma_gemm_body<K, RELU>(blockIdx.x - gridA, lds, Ab, Bwb, biasb, Ob, OSb, OOb, Mb);
}

// ---------------------------------------------------------------------------
// Edge classifier, bucket-direct + XCD-pinned (R7): bid encoding keeps all
// 16 slices of bucket b on XCD b%8, whose L2 holds the 64KB P-window.
// ---------------------------------------------------------------------------
__global__ __launch_bounds__(256) void k_edge_bkt(
    const ushortT* __restrict__ P, const ushortT* __restrict__ Q,
    const uint32_t* __restrict__ tcnt, const uint64_t* __restrict__ bktT,
    const float* __restrict__ wc2, const float* __restrict__ bc2,
    float* __restrict__ out)
{
    const int x = blockIdx.x & 7;          // = b & 7  (XCD id)
    const int s = (blockIdx.x >> 3) & 15;  // slice 0..15
    const int g = blockIdx.x >> 7;         // = b >> 3
    const int b = g * 8 + x;
    if (b >= NB) return;
    int n = (int)tcnt[b];
    if (n > TCAP) n = TCAP;
    const uint64_t* bkt = bktT + (size_t)b * TCAP;
    const int lane = threadIdx.x & 63;
    const int slot = ((threadIdx.x >> 6) << 2) + (lane >> 4);  // 0..15
    const int c8 = lane & 15;

    const float4 w0 = ((const float4*)wc2)[c8 * 2];
    const float4 w1 = ((const float4*)wc2)[c8 * 2 + 1];
    const float bb = bc2[0];
    const ushortT* Pb = P + (size_t)(b << 8) * 128;

    const int lo = (int)(((long long)n * s) >> 4);
    const int hi = (int)(((long long)n * (s + 1)) >> 4);
    for (int i = lo + slot; i < hi; i += 16) {
        const uint64_t v = bkt[i];
        const int c   = (int)(v & 0xFFFFFu);
        const int eid = (int)((v >> 20) & 0xFFFFFu);
        const int rl  = (int)(v >> 40);
        const uint4 pv = *(const uint4*)(Pb + (size_t)rl * 128 + c8 * 8);
        const uint4 qv = *(const uint4*)(Q + (size_t)c * 128 + c8 * 8);
        float sv = edot8(pv, qv, w0, w1);
        sv += __shfl_xor(sv, 1);
        sv += __shfl_xor(sv, 2);
        sv += __shfl_xor(sv, 4);
        sv += __shfl_xor(sv, 8);
        if (c8 == 0) out[eid] = sv + bb;
    }
}

// ---------------------------------------------------------------------------
// Host launcher
// ---------------------------------------------------------------------------
extern "C" void kernel_launch(void* const* d_in, const int* in_sizes, int n_in,
                              void* d_out, int out_size, void* d_ws, size_t ws_size,
                              hipStream_t stream)
{
    const float* x_user  = (const float*)d_in[0];
    const float* x_merch = (const float*)d_in[1];
    const int*   e_um    = (const int*)d_in[2];
    const int*   e_mu    = (const int*)d_in[3];
    const int*   tgt     = (const int*)d_in[4];
    const float* W1_um_l = (const float*)d_in[5];
    const float* b1_um_l = (const float*)d_in[6];
    const float* W1_um_r = (const float*)d_in[7];
    const float* W1_mu_l = (const float*)d_in[8];
    const float* b1_mu_l = (const float*)d_in[9];
    const float* W1_mu_r = (const float*)d_in[10];
    const float* W2_um_l = (const float*)d_in[11];
    const float* b2_um_l = (const float*)d_in[12];
    const float* W2_um_r = (const float*)d_in[13];
    const float* W2_mu_l = (const float*)d_in[14];
    const float* b2_mu_l = (const float*)d_in[15];
    const float* W2_mu_r = (const float*)d_in[16];
    const float* Wc1     = (const float*)d_in[17];
    const float* bc1     = (const float*)d_in[18];
    const float* Wc2     = (const float*)d_in[19];
    const float* bc2     = (const float*)d_in[20];
    float* out = (float*)d_out;

    // ---- workspace carve-up (u32 words, 64-word aligned)
    uint32_t* B = (uint32_t*)d_ws;
    size_t pos = 0;
    auto take = [&](size_t n) { size_t p = pos; pos += (n + 63) & ~(size_t)63; return p; };

    // zeroed-each-launch counter region (contiguous at base)
    uint32_t* tcnt = (uint32_t*)(B + take(NB));          // target bucket counts
    uint32_t* cntA = (uint32_t*)(B + take(N_MERCHC));    // um: per-merchant degree
    uint32_t* cntB = (uint32_t*)(B + take(N_USERC));     // mu: per-user degree
    const size_t cnt_words = pos;
    int* srcsA = (int*)(B + take((size_t)N_MERCHC * DCAP));  // um direct bins (12.8MB)
    int* srcsB = (int*)(B + take((size_t)N_USERC  * DCAP));  // mu direct bins
    uint64_t* bktT = (uint64_t*)(B + take((size_t)NB * TCAP * 2));  // target buckets
    ushortT* A1u = (ushortT*)(B + take((size_t)N_USERC  * 128 / 2));  // [mean1_u | x_u]
    ushortT* A1m = (ushortT*)(B + take((size_t)N_MERCHC * 128 / 2));  // [mean1_m | x_m]
    ushortT* A2u = (ushortT*)(B + take((size_t)N_USERC  * 256 / 2));  // [mean2_u | h_u]
    ushortT* A2m = (ushortT*)(B + take((size_t)N_MERCHC * 256 / 2));  // [mean2_m | h_m]
    ushortT* B1m = (ushortT*)(B + take(8192));          // [W1_um_l | W1_um_r] bf16
    ushortT* B1u = (ushortT*)(B + take(8192));          // [W1_mu_l | W1_mu_r]
    ushortT* WPQ = (ushortT*)(B + take(32768));         // fused [2][128][256] bf16
    float*   bPQ = (float*)(B + take(256));             // fused biases [2][128] fp32

    // P/Q: written by classifier GEMMs (A1 dead after GEMM1), read by k_edge
    ushortT* Pbf = A1u;
    ushortT* Qbf = A1m;
    (void)ws_size; (void)in_sizes; (void)n_in; (void)out_size;

    // 1) zero degree/bucket counters (~400KB)
    hipMemsetAsync(d_ws, 0, cnt_words * sizeof(uint32_t), stream);

    // 2) fused prep: direct-place um/mu + target buckets + casts + weight fusion
    k_prep<<<PREP_TOT, 256, 0, stream>>>(
        x_user, x_merch, A1u, A1m,
        W1_um_l, W1_um_r, W1_mu_l, W1_mu_r, B1m, B1u,
        Wc1, W2_mu_l, W2_mu_r, W2_um_l, W2_um_r, bc1, b2_mu_l, b2_um_l, WPQ, bPQ,
        e_um, e_um + NEC, e_mu, e_mu + NEC, tgt, tgt + NTC,
        tcnt, cntA, cntB, srcsA, srcsB, bktT);

    // 3) layer-1 aggregates: gather x halves, write mean1 halves (bf16)
    const int agrid = 50000 / 4;
    k_agg<64><<<2 * agrid, 256, 0, stream>>>(
        A1u, cntA, srcsA, A1m,
        A1m, cntB, srcsB, A1u, N_MERCHC);

    // 4) layer-1 MFMA GEMM pair: h = relu(A1 @ B1^T + b1) -> A2 cols 128..255
    const int ggrid = (50000 + 255) / 256;
    k_mfma_gemm2<128, true><<<2 * ggrid, 256, 0, stream>>>(
        A1m, B1m, b1_um_l, A2m, 256, 128, N_MERCHC,
        A1u, B1u, b1_mu_l, A2u, 256, 128, N_USERC, ggrid);

    // 5) layer-2 aggregates: gather h halves, write mean2 halves (bf16)
    k_agg<128><<<2 * agrid, 256, 0, stream>>>(
        A2u, cntA, srcsA, A2m,
        A2m, cntB, srcsB, A2u, N_MERCHC);

    // 6) fused classifier MFMA GEMM pair: P = A2u @ WP^T + bP ; Q = A2m @ WQ^T + bQ
    k_mfma_gemm2<256, false><<<2 * ggrid, 256, 0, stream>>>(
        A2u, WPQ,         bPQ,       Pbf, 128, 0, N_USERC,
        A2m, WPQ + 32768, bPQ + 128, Qbf, 128, 0, N_MERCHC, ggrid);

    // 7) per-edge, bucket-direct + XCD-pinned: grid = ceil(NB/8)*8*16 = 3200
    k_edge_bkt<<<((NB + 7) / 8) * 128, 256, 0, stream>>>(Pbf, Qbf, tcnt, bktT,
                                                         Wc2, bc2, out);
}

// Round 9
// 335.248 us; speedup vs baseline: 1.3384x; 1.3384x over previous
//
#include <hip/hip_runtime.h>
#include <hip/hip_bf16.h>
#include <stdint.h>

#define N_USERC  50000
#define N_MERCHC 50000
#define NEC      1000000   // edges per direction
#define NTC      500000    // target edges

#define NB    196          // buckets (256 dsts each: bucket = id >> 8)
#define BCAP  8192         // pairs per bucket (mean 5120, sigma ~72)
#define TCAP  4096         // target pairs per bucket (mean 2560, +30 sigma)
#define ECHUNK 2048        // edges per bucket-pass block (8/thread)
#define BPT   489          // bucket-pass blocks per edge type = ceil(NEC/ECHUNK)
#define BPTT  245          // target bucket-pass blocks = ceil(NTC/ECHUNK)

// k_prep fused-grid offsets — bucket passes FIRST (long pole starts at t=0)
#define PREP_BKT   (2 * BPT + BPTT)       // [0, 1223) bucket passes (um, mu, tgt)
#define PREP_CASTX (PREP_BKT + 3125)      // x casts  (800000/256 blocks)
#define PREP_CASTW (PREP_CASTX + 16)      // layer-1 weight casts
#define PREP_TOT   (PREP_CASTW + 257)     // classifier weight fusion

typedef unsigned short ushortT;
typedef __attribute__((ext_vector_type(8))) short short8;     // 8 bf16 (MFMA frag)
typedef __attribute__((ext_vector_type(8))) unsigned short ushort8;
typedef __attribute__((ext_vector_type(4))) float f32x4;
typedef __attribute__((ext_vector_type(2))) float f32x2;

__device__ __forceinline__ unsigned short f2bf(float f)
{
    const unsigned u = __float_as_uint(f);
    const unsigned r = u + 0x7fffu + ((u >> 16) & 1u);   // RNE
    return (unsigned short)(r >> 16);
}
__device__ __forceinline__ float bfhi(unsigned u) { return __uint_as_float(u & 0xffff0000u); }
__device__ __forceinline__ float bflo(unsigned u) { return __uint_as_float(u << 16); }

// packed accumulate: 4x v_pk_add_f32 + 8 unpacks per 16B
__device__ __forceinline__ void acc8p(f32x2* a, const uint4 v)
{
    a[0] += (f32x2){bflo(v.x), bfhi(v.x)};
    a[1] += (f32x2){bflo(v.y), bfhi(v.y)};
    a[2] += (f32x2){bflo(v.z), bfhi(v.z)};
    a[3] += (f32x2){bflo(v.w), bfhi(v.w)};
}

// relu(p+q).w over 8 bf16 pairs
__device__ __forceinline__ float edot8(const uint4 pv, const uint4 qv,
                                       const float4 w0, const float4 w1)
{
    return fmaxf(bflo(pv.x) + bflo(qv.x), 0.f) * w0.x
         + fmaxf(bfhi(pv.x) + bfhi(qv.x), 0.f) * w0.y
         + fmaxf(bflo(pv.y) + bflo(qv.y), 0.f) * w0.z
         + fmaxf(bfhi(pv.y) + bfhi(qv.y), 0.f) * w0.w
         + fmaxf(bflo(pv.z) + bflo(qv.z), 0.f) * w1.x
         + fmaxf(bfhi(pv.z) + bfhi(qv.z), 0.f) * w1.y
         + fmaxf(bflo(pv.w) + bflo(qv.w), 0.f) * w1.z
         + fmaxf(bfhi(pv.w) + bfhi(qv.w), 0.f) * w1.w;
}

// ---------------------------------------------------------------------------
// Fused prep kernel. Bucket passes now LDS-SORT each 2048-edge chunk by
// bucket before writing out (R8 lesson: the scattered per-wave bucket writes
// were the 60us pole — 64 lanes hit 64 different lines per instruction).
// Out-phase writes are linear over the sorted LDS array: consecutive lanes
// write consecutive addresses within each bucket's contiguous global run.
// Entries carry the FULL dst id (c < 50K fits 16 bits) so consumers
// recompute bucket = entry>>24 and local dst = (entry>>16)&255.
// ---------------------------------------------------------------------------
__global__ __launch_bounds__(256) void k_prep(
    const float* __restrict__ xu, const float* __restrict__ xm,
    ushortT* __restrict__ A1u, ushortT* __restrict__ A1m,
    const float* __restrict__ W1um_l, const float* __restrict__ W1um_r,
    const float* __restrict__ W1mu_l, const float* __restrict__ W1mu_r,
    ushortT* __restrict__ B1m, ushortT* __restrict__ B1u,
    const float* __restrict__ Wc1,
    const float* __restrict__ W2mu_l, const float* __restrict__ W2mu_r,
    const float* __restrict__ W2um_l, const float* __restrict__ W2um_r,
    const float* __restrict__ bc1,
    const float* __restrict__ b2mu_l, const float* __restrict__ b2um_l,
    ushortT* __restrict__ WPQ, float* __restrict__ bPQ,
    const int* __restrict__ rowA, const int* __restrict__ colA,
    const int* __restrict__ rowB, const int* __restrict__ colB,
    const int* __restrict__ tgr, const int* __restrict__ tgc,
    uint32_t* __restrict__ gcnt, uint32_t* __restrict__ bktA, uint32_t* __restrict__ bktB,
    uint64_t* __restrict__ bktT)
{
    __shared__ uint32_t hist[NB], gbase[NB], cur[NB];
    __shared__ uint32_t scan[256];
    __shared__ __align__(8) uint32_t sEnt[2 * ECHUNK];   // 16KB: u32[2048] or u64[2048]
    const int bid = blockIdx.x;
    const int tx = threadIdx.x;

    if (bid < PREP_BKT) {
        // ---- bucket passes (um / mu u32; target u64)
        const int type = (bid >= 2 * BPT) ? 2 : (bid >= BPT ? 1 : 0);
        const int cb = bid - (type == 2 ? 2 * BPT : type * BPT);
        const int* col = (type == 2) ? tgr : (type ? colB : colA);   // bucket key (dst)
        const int* row = (type == 2) ? tgc : (type ? rowB : rowA);   // payload
        uint32_t* bkt = type ? bktB : bktA;                          // types 0/1
        uint32_t* gc = gcnt + type * NB;
        const int nE  = (type == 2) ? NTC : NEC;

        const int e0 = cb * ECHUNK;
        const int e1 = (e0 + ECHUNK < nE) ? e0 + ECHUNK : nE;
        const int nv = e1 - e0;               // valid entries this chunk

        for (int i = tx; i < NB; i += 256) { hist[i] = 0; cur[i] = 0; }
        __syncthreads();

        int cs[8], rs[8];
#pragma unroll
        for (int q = 0; q < 8; ++q) {
            const int i = e0 + tx + q * 256;
            int c = -1, r = 0;
            if (i < e1) { c = col[i]; r = row[i]; atomicAdd(&hist[c >> 8], 1u); }
            cs[q] = c; rs[q] = r;
        }
        __syncthreads();
        // global bases + local exclusive scan of hist
        for (int i = tx; i < NB; i += 256)
            gbase[i] = atomicAdd(&gc[i], hist[i]);
        scan[tx] = (tx < NB) ? hist[tx] : 0;
        for (int d = 1; d < 256; d <<= 1) {
            __syncthreads();
            const uint32_t a = (tx >= d) ? scan[tx - d] : 0;
            __syncthreads();
            scan[tx] += a;
        }
        __syncthreads();
        if (tx < NB) scan[tx] -= hist[tx];    // exclusive local base
        __syncthreads();

        if (type < 2) {
            // scatter into bucket-sorted LDS order (full c in high 16 bits)
#pragma unroll
            for (int q = 0; q < 8; ++q) {
                if (cs[q] >= 0) {
                    const int b = cs[q] >> 8;
                    const uint32_t s = scan[b] + atomicAdd(&cur[b], 1u);
                    sEnt[s] = ((uint32_t)cs[q] << 16) | (uint32_t)rs[q];
                }
            }
            __syncthreads();
            // linear out: consecutive lanes -> consecutive addrs per bucket run
            for (int j = tx; j < nv; j += 256) {
                const uint32_t e = sEnt[j];
                const uint32_t b = e >> 24;
                const uint32_t addr = gbase[b] + ((uint32_t)j - scan[b]);
                if (addr < (uint32_t)BCAP) bkt[(size_t)b * BCAP + addr] = e;
            }
        } else {
            uint64_t* sE64 = (uint64_t*)sEnt;
            // entry: full r (16b) << 40 | eid << 20 | c  (bucket = entry >> 48)
#pragma unroll
            for (int q = 0; q < 8; ++q) {
                if (cs[q] >= 0) {
                    const int i = e0 + tx + q * 256;
                    const int b = cs[q] >> 8;
                    const uint32_t s = scan[b] + atomicAdd(&cur[b], 1u);
                    sE64[s] = ((uint64_t)(uint32_t)cs[q] << 40)
                            | ((uint64_t)(uint32_t)i << 20)
                            | (uint64_t)(uint32_t)rs[q];
                }
            }
            __syncthreads();
            for (int j = tx; j < nv; j += 256) {
                const uint64_t e = sE64[j];
                const uint32_t b = (uint32_t)(e >> 48);
                const uint32_t addr = gbase[b] + ((uint32_t)j - scan[b]);
                if (addr < (uint32_t)TCAP) bktT[(size_t)b * TCAP + addr] = e;
            }
        }
    } else if (bid < PREP_CASTX) {
        // ---- cast_x: A1[row] = [ (mean later) | bf16(x[row]) ]
        const int idx = (bid - PREP_BKT) * 256 + tx;
        if (idx >= 800000) return;
        const int which = idx / 400000;
        const int rem = idx - which * 400000;
        const int row = rem >> 3;
        const int c8 = rem & 7;
        const float* x = which ? xm : xu;
        ushortT* A = which ? A1m : A1u;
        const float4 v0 = *(const float4*)(x + (size_t)row * 64 + c8 * 8);
        const float4 v1 = *(const float4*)(x + (size_t)row * 64 + c8 * 8 + 4);
        ushort8 o;
        o[0] = f2bf(v0.x); o[1] = f2bf(v0.y); o[2] = f2bf(v0.z); o[3] = f2bf(v0.w);
        o[4] = f2bf(v1.x); o[5] = f2bf(v1.y); o[6] = f2bf(v1.z); o[7] = f2bf(v1.w);
        *(ushort8*)(A + (size_t)row * 128 + 64 + c8 * 8) = o;
    } else if (bid < PREP_CASTW) {
        // ---- cast_w1: B1[n][k] = k<64 ? Wl[n][k] : Wr[n][k-64]
        const int idx = (bid - PREP_CASTX) * 256 + tx;
        if (idx >= 4096) return;
        const int which = idx >> 11;
        const int rem = idx & 2047;
        const int n = rem >> 4;
        const int k0 = (rem & 15) * 8;
        const float* Wl = which ? W1mu_l : W1um_l;
        const float* Wr = which ? W1mu_r : W1um_r;
        const float* src = (k0 < 64) ? Wl + (size_t)n * 64 + k0
                                     : Wr + (size_t)n * 64 + (k0 - 64);
        const float4 v0 = *(const float4*)src;
        const float4 v1 = *(const float4*)(src + 4);
        ushort8 o;
        o[0] = f2bf(v0.x); o[1] = f2bf(v0.y); o[2] = f2bf(v0.z); o[3] = f2bf(v0.w);
        o[4] = f2bf(v1.x); o[5] = f2bf(v1.y); o[6] = f2bf(v1.z); o[7] = f2bf(v1.w);
        ushortT* O = which ? B1u : B1m;
        *(ushort8*)(O + (size_t)n * 128 + k0) = o;
    } else {
        // ---- wcombine: WP[j][k] = Wc1a[j,:] @ W2_mu_{l|r}[:,k] etc., bf16
        const int idx = (bid - PREP_CASTW) * 256 + tx;
        if (idx < 65536) {
            const int q = idx >> 15;
            const int j = (idx >> 8) & 127;
            const int k = idx & 255;
            const int kk = k & 127;
            const float* W2 = q ? (k < 128 ? W2um_l : W2um_r)
                                : (k < 128 ? W2mu_l : W2mu_r);
            const float* wrow = Wc1 + (size_t)j * 256 + q * 128;
            float s = 0.f;
            for (int i = 0; i < 128; ++i)
                s = fmaf(wrow[i], W2[(size_t)i * 128 + kk], s);
            WPQ[idx] = f2bf(s);
        } else if (idx < 65536 + 256) {
            const int r = idx - 65536;
            const int q = r >> 7, j = r & 127;
            const float* wrow = Wc1 + (size_t)j * 256 + q * 128;
            const float* b2 = q ? b2um_l : b2mu_l;
            float s = (q == 0) ? bc1[j] : 0.f;
            for (int i = 0; i < 128; ++i) s = fmaf(wrow[i], b2[i], s);
            bPQ[r] = s;
        }
    }
}

// ---------------------------------------------------------------------------
// CSR place pass (um/mu only) with inline bucket-base scan. 512 thr/block.
// Entries carry full dst in high 16 bits: local dst = (v>>16)&255.
// ---------------------------------------------------------------------------
__global__ __launch_bounds__(512) void k_bplace(
    const uint32_t* __restrict__ gcnt,
    const uint32_t* __restrict__ bktA, const uint32_t* __restrict__ bktB,
    int* __restrict__ off_um, int* __restrict__ srcs_um,
    int* __restrict__ off_mu, int* __restrict__ srcs_mu)
{
    __shared__ uint32_t sb[256], cnt[256], loff[256], cur[256];
    const int type = (blockIdx.x >= NB) ? 1 : 0;
    const int b = blockIdx.x - type * NB;
    const uint32_t* bkt = (type ? bktB : bktA) + (size_t)b * BCAP;
    int* offp = type ? off_mu : off_um;
    int* srcs = type ? srcs_mu : srcs_um;
    const int t = threadIdx.x;

    // inline exclusive scan of this type's bucket counts (lanes 0..255)
    if (t < 256) sb[t] = (t < NB) ? gcnt[type * NB + t] : 0;
    for (int d = 1; d < 256; d <<= 1) {
        __syncthreads();
        uint32_t a = 0;
        if (t < 256 && t >= d) a = sb[t - d];
        __syncthreads();
        if (t < 256) sb[t] += a;
    }
    __syncthreads();
    const int n = (int)gcnt[type * NB + b];
    const uint32_t gbase = sb[b] - (uint32_t)n;   // exclusive prefix at b
    if (blockIdx.x == 0 && t == 0)  off_um[N_MERCHC] = NEC;
    if (blockIdx.x == NB && t == 0) off_mu[N_USERC] = NEC;

    if (t < 256) { cnt[t] = 0; cur[t] = 0; }
    __syncthreads();
    for (int i = t; i < n; i += 512)
        atomicAdd(&cnt[(bkt[i] >> 16) & 255], 1u);
    __syncthreads();
    if (t < 256) loff[t] = cnt[t];
    for (int d = 1; d < 256; d <<= 1) {
        __syncthreads();
        uint32_t a = 0;
        if (t < 256 && t >= d) a = loff[t - d];
        __syncthreads();
        if (t < 256) loff[t] += a;
    }
    __syncthreads();
    if (t < 256) loff[t] -= cnt[t];               // exclusive local prefix
    __syncthreads();
    if (t < 256) {
        const int dst0 = b << 8;
        if (dst0 + t < N_USERC) offp[dst0 + t] = (int)(gbase + loff[t]);
    }
    for (int i = t; i < n; i += 512) {
        const uint32_t v = bkt[i];
        const uint32_t ld = (v >> 16) & 255;
        const uint32_t p = gbase + loff[ld] + atomicAdd(&cur[ld], 1u);
        srcs[p] = (int)(v & 0xFFFFu);
    }
}

// ---------------------------------------------------------------------------
// Mean aggregation over interleaved bf16 tables, both directions per launch.
// R3 version (59.4us, ~3.7 TB/s beyond-L2 — fabric-bound local optimum).
// ---------------------------------------------------------------------------
template <int D>
__global__ __launch_bounds__(256) void k_agg(
    const ushortT* __restrict__ gA, const int* __restrict__ offsA,
    const int* __restrict__ srcsA, ushortT* __restrict__ oA,
    const ushortT* __restrict__ gB, const int* __restrict__ offsB,
    const int* __restrict__ srcsB, ushortT* __restrict__ oB, int ndst)
{
    constexpr int LPE = D / 8;        // lanes per edge row (16 / 8)
    constexpr int EPW = 64 / LPE;     // edges per round (4 / 8)
    constexpr int UNR = (D == 128) ? 8 : 4;   // rounds per chunk
    constexpr int STR = 2 * D;        // interleaved row stride (elems)
    constexpr unsigned RB = 4 * D;    // row stride in bytes
    const int half = gridDim.x >> 1;
    const int type = (blockIdx.x >= half) ? 1 : 0;
    const int cb = blockIdx.x - type * half;
    const ushortT* g = type ? gB : gA;
    const int* offs  = type ? offsB : offsA;
    const int* srcs  = type ? srcsB : srcsA;
    ushortT* om      = type ? oB : oA;

    const int wid = cb * 4 + (threadIdx.x >> 6);
    if (wid >= ndst) return;
    const int lane = threadIdx.x & 63;
    const int sub  = lane / LPE;
    const int c4   = lane % LPE;

    const int b = offs[wid], e = offs[wid + 1];
    const int deg = e - b;
    // per-lane column base: row s contributes bytes [s*RB + 2*D + c4*16, +16)
    const char* gDc = (const char*)(g + D) + c4 * 16;

    f32x2 a0[4], a1[4];
#pragma unroll
    for (int j = 0; j < 4; ++j) { a0[j] = (f32x2){0.f, 0.f}; a1[j] = (f32x2){0.f, 0.f}; }

    if (deg <= 64) {
        // whole adjacency list in registers via one coalesced load + shfl
        const int sidx = (b + lane < NEC) ? b + lane : NEC - 1;
        const int src_l = srcs[sidx];
        for (int t0 = 0; t0 < deg; t0 += UNR * EPW) {
            uint4 v[UNR];
#pragma unroll
            for (int r = 0; r < UNR; ++r) {
                const int j = t0 + r * EPW + sub;      // j <= 63 by construction
                const int s = __shfl(src_l, j);
                v[r] = (uint4){0u, 0u, 0u, 0u};
                if (j < deg)
                    v[r] = *(const uint4*)(gDc + (unsigned)s * RB);
            }
            __builtin_amdgcn_sched_barrier(0);         // pin: all gathers issued first
#pragma unroll
            for (int r = 0; r < UNR; ++r)
                acc8p((r & 1) ? a1 : a0, v[r]);
        }
    } else {
        // rare fallback: serial pairwise loop
        int i = b + sub;
        for (; i + EPW < e; i += 2 * EPW) {
            const uint4 v0 = *(const uint4*)(gDc + (unsigned)srcs[i] * RB);
            const uint4 v1 = *(const uint4*)(gDc + (unsigned)srcs[i + EPW] * RB);
            acc8p(a0, v0);
            acc8p(a1, v1);
        }
        if (i < e) {
            const uint4 v = *(const uint4*)(gDc + (unsigned)srcs[i] * RB);
            acc8p(a0, v);
        }
    }

    float r[8];
#pragma unroll
    for (int j = 0; j < 4; ++j) {
        r[2 * j]     = a0[j].x + a1[j].x;
        r[2 * j + 1] = a0[j].y + a1[j].y;
    }
#pragma unroll
    for (int m = LPE; m < 64; m <<= 1) {
#pragma unroll
        for (int j = 0; j < 8; ++j) r[j] += __shfl_xor(r[j], m);
    }
    if (sub == 0) {
        const float inv = 1.0f / (float)(deg > 1 ? deg : 1);
        ushort8 o;
#pragma unroll
        for (int j = 0; j < 8; ++j) o[j] = f2bf(r[j] * inv);
        *(ushort8*)(om + (size_t)wid * STR + c4 * 8) = o;
    }
}

// ---------------------------------------------------------------------------
// MFMA bf16 GEMM: Out[m][0:128] = act(A[m][0:K] @ W^T + bias), bf16 out.
// ---------------------------------------------------------------------------
template <int K, bool RELU>
__device__ __forceinline__ void mfma_gemm_body(
    int cb, float (*lds)[16][132],
    const ushortT* __restrict__ A, const ushortT* __restrict__ Bw,
    const float* __restrict__ bias,
    ushortT* __restrict__ Obf, int OS, int OO, int M)
{
    const int tx = threadIdx.x;
    const int wid = tx >> 6;
    const int lane = tx & 63;
    const int ln = lane & 15;
    const int quad = lane >> 4;
    const int m0 = cb * 256 + wid * 64;

    const ushortT* ap[4];
#pragma unroll
    for (int i = 0; i < 4; ++i) {
        int arow = m0 + i * 16 + ln; if (arow >= M) arow = M - 1;
        ap[i] = A + (size_t)arow * K + quad * 8;
    }

    f32x4 acc[4][8];
#pragma unroll
    for (int i = 0; i < 4; ++i)
#pragma unroll
        for (int nt = 0; nt < 8; ++nt) acc[i][nt] = (f32x4){0.f, 0.f, 0.f, 0.f};

#pragma unroll
    for (int kc = 0; kc < K / 32; ++kc) {
        short8 a[4];
#pragma unroll
        for (int i = 0; i < 4; ++i) a[i] = *(const short8*)(ap[i] + kc * 32);
#pragma unroll
        for (int nt = 0; nt < 8; ++nt) {
            const short8 b = *(const short8*)(Bw + (size_t)(nt * 16 + ln) * K + kc * 32 + quad * 8);
#pragma unroll
            for (int i = 0; i < 4; ++i)
                acc[i][nt] = __builtin_amdgcn_mfma_f32_16x16x32_bf16(a[i], b, acc[i][nt], 0, 0, 0);
        }
    }

    float (*t)[132] = lds[wid];
#pragma unroll
    for (int i = 0; i < 4; ++i) {
#pragma unroll
        for (int nt = 0; nt < 8; ++nt) {
            const float bv = bias[nt * 16 + ln];
#pragma unroll
            for (int r = 0; r < 4; ++r) {
                float v = acc[i][nt][r] + bv;
                if (RELU) v = fmaxf(v, 0.f);
                t[quad * 4 + r][nt * 16 + ln] = v;
            }
        }
#pragma unroll
        for (int p = 0; p < 4; ++p) {
            const int row = p * 4 + quad;
            const int gr = m0 + i * 16 + row;
            if (gr < M) {
                const float4 v0 = *(const float4*)&t[row][ln * 8];
                const float4 v1 = *(const float4*)&t[row][ln * 8 + 4];
                ushort8 o;
                o[0] = f2bf(v0.x); o[1] = f2bf(v0.y); o[2] = f2bf(v0.z); o[3] = f2bf(v0.w);
                o[4] = f2bf(v1.x); o[5] = f2bf(v1.y); o[6] = f2bf(v1.z); o[7] = f2bf(v1.w);
                *(ushort8*)(Obf + (size_t)gr * OS + OO + ln * 8) = o;
            }
        }
    }
}

template <int K, bool RELU>
__global__ __launch_bounds__(256) void k_mfma_gemm2(
    const ushortT* __restrict__ Aa, const ushortT* __restrict__ Bwa,
    const float* __restrict__ biasa, ushortT* __restrict__ Oa, int OSa, int OOa, int Ma,
    const ushortT* __restrict__ Ab, const ushortT* __restrict__ Bwb,
    const float* __restrict__ biasb, ushortT* __restrict__ Ob, int OSb, int OOb, int Mb,
    int gridA)
{
    __shared__ float lds[4][16][132];
    if ((int)blockIdx.x < gridA)
        mfma_gemm_body<K, RELU>(blockIdx.x, lds, Aa, Bwa, biasa, Oa, OSa, OOa, Ma);
    else
        mfma_gemm_body<K, RELU>(blockIdx.x - gridA, lds, Ab, Bwb, biasb, Ob, OSb, OOb, Mb);
}

// ---------------------------------------------------------------------------
// Edge classifier, bucket-direct + XCD-pinned (R7): bid encoding keeps all
// 16 slices of bucket b on XCD b%8, whose L2 holds the 64KB P-window.
// Entry now carries full r: rl = (v>>40)&255.
// ---------------------------------------------------------------------------
__global__ __launch_bounds__(256) void k_edge_bkt(
    const ushortT* __restrict__ P, const ushortT* __restrict__ Q,
    const uint32_t* __restrict__ gcnt, const uint64_t* __restrict__ bktT,
    const float* __restrict__ wc2, const float* __restrict__ bc2,
    float* __restrict__ out)
{
    const int x = blockIdx.x & 7;          // = b & 7  (XCD id)
    const int s = (blockIdx.x >> 3) & 15;  // slice 0..15
    const int g = blockIdx.x >> 7;         // = b >> 3
    const int b = g * 8 + x;
    if (b >= NB) return;
    int n = (int)gcnt[2 * NB + b];
    if (n > TCAP) n = TCAP;
    const uint64_t* bkt = bktT + (size_t)b * TCAP;
    const int lane = threadIdx.x & 63;
    const int slot = ((threadIdx.x >> 6) << 2) + (lane >> 4);  // 0..15
    const int c8 = lane & 15;

    const float4 w0 = ((const float4*)wc2)[c8 * 2];
    const float4 w1 = ((const float4*)wc2)[c8 * 2 + 1];
    const float bb = bc2[0];
    const ushortT* Pb = P + (size_t)(b << 8) * 128;

    const int lo = (int)(((long long)n * s) >> 4);
    const int hi = (int)(((long long)n * (s + 1)) >> 4);
    for (int i = lo + slot; i < hi; i += 16) {
        const uint64_t v = bkt[i];
        const int c   = (int)(v & 0xFFFFFu);
        const int eid = (int)((v >> 20) & 0xFFFFFu);
        const int rl  = (int)((v >> 40) & 255u);
        const uint4 pv = *(const uint4*)(Pb + (size_t)rl * 128 + c8 * 8);
        const uint4 qv = *(const uint4*)(Q + (size_t)c * 128 + c8 * 8);
        float sv = edot8(pv, qv, w0, w1);
        sv += __shfl_xor(sv, 1);
        sv += __shfl_xor(sv, 2);
        sv += __shfl_xor(sv, 4);
        sv += __shfl_xor(sv, 8);
        if (c8 == 0) out[eid] = sv + bb;
    }
}

// ---------------------------------------------------------------------------
// Host launcher
// ---------------------------------------------------------------------------
extern "C" void kernel_launch(void* const* d_in, const int* in_sizes, int n_in,
                              void* d_out, int out_size, void* d_ws, size_t ws_size,
                              hipStream_t stream)
{
    const float* x_user  = (const float*)d_in[0];
    const float* x_merch = (const float*)d_in[1];
    const int*   e_um    = (const int*)d_in[2];
    const int*   e_mu    = (const int*)d_in[3];
    const int*   tgt     = (const int*)d_in[4];
    const float* W1_um_l = (const float*)d_in[5];
    const float* b1_um_l = (const float*)d_in[6];
    const float* W1_um_r = (const float*)d_in[7];
    const float* W1_mu_l = (const float*)d_in[8];
    const float* b1_mu_l = (const float*)d_in[9];
    const float* W1_mu_r = (const float*)d_in[10];
    const float* W2_um_l = (const float*)d_in[11];
    const float* b2_um_l = (const float*)d_in[12];
    const float* W2_um_r = (const float*)d_in[13];
    const float* W2_mu_l = (const float*)d_in[14];
    const float* b2_mu_l = (const float*)d_in[15];
    const float* W2_mu_r = (const float*)d_in[16];
    const float* Wc1     = (const float*)d_in[17];
    const float* bc1     = (const float*)d_in[18];
    const float* Wc2     = (const float*)d_in[19];
    const float* bc2     = (const float*)d_in[20];
    float* out = (float*)d_out;

    // ---- workspace carve-up (u32 words, 64-word aligned)
    uint32_t* B = (uint32_t*)d_ws;
    size_t pos = 0;
    auto take = [&](size_t n) { size_t p = pos; pos += (n + 63) & ~(size_t)63; return p; };

    uint32_t* gcnt = (uint32_t*)(B + take(3 * NB));     // zeroed each launch
    const size_t cnt_words = pos;
    int* off_um  = (int*)(B + take(N_MERCHC + 1));
    int* srcs_um = (int*)(B + take(NEC));
    int* off_mu  = (int*)(B + take(N_USERC + 1));
    int* srcs_mu = (int*)(B + take(NEC));
    uint64_t* bktT = (uint64_t*)(B + take((size_t)NB * TCAP * 2));  // dedicated:
                                                        // must survive until k_edge
    ushortT* A1u = (ushortT*)(B + take((size_t)N_USERC  * 128 / 2));  // [mean1_u | x_u]
    ushortT* A1m = (ushortT*)(B + take((size_t)N_MERCHC * 128 / 2));  // [mean1_m | x_m]
    ushortT* A2u = (ushortT*)(B + take((size_t)N_USERC  * 256 / 2));  // [mean2_u | h_u]
    ushortT* A2m = (ushortT*)(B + take((size_t)N_MERCHC * 256 / 2));  // [mean2_m | h_m]
    ushortT* B1m = (ushortT*)(B + take(8192));          // [W1_um_l | W1_um_r] bf16
    ushortT* B1u = (ushortT*)(B + take(8192));          // [W1_mu_l | W1_mu_r]
    ushortT* WPQ = (ushortT*)(B + take(32768));         // fused [2][128][256] bf16
    float*   bPQ = (float*)(B + take(256));             // fused biases [2][128] fp32

    // ---- aliases (lifetimes):
    // um/mu buckets live only through k_bplace; A2m written later (GEMM1/agg2)
    uint32_t* bktA = (uint32_t*)A2m;
    uint32_t* bktB = bktA + (size_t)NB * BCAP;          // 3.2M words <= 6.4M
    // P/Q: written by classifier GEMMs (A1 dead after GEMM1), read by k_edge
    ushortT* Pbf = A1u;
    ushortT* Qbf = A1m;
    (void)ws_size; (void)in_sizes; (void)n_in; (void)out_size;

    // 1) zero bucket counters
    hipMemsetAsync(d_ws, 0, cnt_words * sizeof(uint32_t), stream);

    // 2) fused prep: LDS-sorted bucket passes + x casts + weight casts + fusion
    k_prep<<<PREP_TOT, 256, 0, stream>>>(
        x_user, x_merch, A1u, A1m,
        W1_um_l, W1_um_r, W1_mu_l, W1_mu_r, B1m, B1u,
        Wc1, W2_mu_l, W2_mu_r, W2_um_l, W2_um_r, bc1, b2_mu_l, b2_um_l, WPQ, bPQ,
        e_um, e_um + NEC, e_mu, e_mu + NEC, tgt, tgt + NTC,
        gcnt, bktA, bktB, bktT);

    // 3) CSR place for um/mu (target edges stay bucket-form)
    k_bplace<<<2 * NB, 512, 0, stream>>>(gcnt, bktA, bktB,
                                         off_um, srcs_um, off_mu, srcs_mu);

    // 4) layer-1 aggregates: gather x halves, write mean1 halves (bf16)
    const int agrid = 50000 / 4;
    k_agg<64><<<2 * agrid, 256, 0, stream>>>(
        A1u, off_um, srcs_um, A1m,
        A1m, off_mu, srcs_mu, A1u, N_MERCHC);

    // 5) layer-1 MFMA GEMM pair: h = relu(A1 @ B1^T + b1) -> A2 cols 128..255
    const int ggrid = (50000 + 255) / 256;
    k_mfma_gemm2<128, true><<<2 * ggrid, 256, 0, stream>>>(
        A1m, B1m, b1_um_l, A2m, 256, 128, N_MERCHC,
        A1u, B1u, b1_mu_l, A2u, 256, 128, N_USERC, ggrid);

    // 6) layer-2 aggregates: gather h halves, write mean2 halves (bf16)
    k_agg<128><<<2 * agrid, 256, 0, stream>>>(
        A2u, off_um, srcs_um, A2m,
        A2m, off_mu, srcs_mu, A2u, N_MERCHC);

    // 7) fused classifier MFMA GEMM pair: P = A2u @ WP^T + bP ; Q = A2m @ WQ^T + bQ
    k_mfma_gemm2<256, false><<<2 * ggrid, 256, 0, stream>>>(
        A2u, WPQ,         bPQ,       Pbf, 128, 0, N_USERC,
        A2m, WPQ + 32768, bPQ + 128, Qbf, 128, 0, N_MERCHC, ggrid);

    // 8) per-edge, bucket-direct + XCD-pinned: grid = ceil(NB/8)*8*16 = 3200
    k_edge_bkt<<<((NB + 7) / 8) * 128, 256, 0, stream>>>(Pbf, Qbf, gcnt, bktT,
                                                         Wc2, bc2, out);
}